// Round 5
// baseline (1154.718 us; speedup 1.0000x reference)
//
#include <hip/hip_runtime.h>
#include <math.h>

#define VOCAB 32000
#define HDIM  512
#define NLAYERS 4
#define BATCH 32
#define TSTEPS 64
typedef unsigned long long ULL;

typedef __attribute__((ext_vector_type(8))) short bf16x8;
typedef __attribute__((ext_vector_type(4))) float f32x4;

static __device__ __forceinline__ unsigned short f2b(float f) {
    union { float f; unsigned u; } v; v.f = f;
    return (unsigned short)((v.u + 0x7FFFu + ((v.u >> 16) & 1u)) >> 16);
}
static __device__ __forceinline__ float sigf(float x) { return 1.0f / (1.0f + __expf(-x)); }

// packed offset of element (m,k) in a [32 rows][1024 k] bf16 operand stored in
// MFMA-fragment order: [k0=k/32][mi=m/16][lane][8]
static __device__ __forceinline__ int apack_off(int m, int k) {
    int k0 = k >> 5, mi = m >> 4;
    int lane = (m & 15) | (((k >> 3) & 3) << 4);
    return ((k0 * 2 + mi) * 64 + lane) * 8 + (k & 7);
}

// ---------------- weight prep (verified round 2/3) ----------------
__global__ void k_prep_w(const float* __restrict__ W_ih, const float* __restrict__ W_hh,
                         unsigned short* __restrict__ wp) {
    const int total = NLAYERS * 64 * 2 * 32 * 64 * 8;  // 8388608
    for (int idx = blockIdx.x * blockDim.x + threadIdx.x; idx < total;
         idx += gridDim.x * blockDim.x) {
        int sub = idx & 7, lane = (idx >> 3) & 63, k0 = (idx >> 9) & 31;
        int ni = (idx >> 14) & 1, bi = (idx >> 15) & 63, l = idx >> 21;
        int r = ni * 16 + (lane & 15);
        int k = k0 * 32 + ((lane >> 4) << 3) + sub;
        int j = (r & 3) * 512 + bi * 8 + (r >> 2);
        float v = (k < 512) ? W_ih[((size_t)l * 2048 + j) * 512 + k]
                            : W_hh[((size_t)l * 2048 + j) * 512 + (k - 512)];
        wp[idx] = f2b(v);
    }
}

__global__ void k_prep_bias(const float* __restrict__ b_ih, const float* __restrict__ b_hh,
                            float* __restrict__ bs) {
    int idx = blockIdx.x * blockDim.x + threadIdx.x;
    if (idx < NLAYERS * 64 * 32) {
        int r = idx & 31, bi = (idx >> 5) & 63, l = idx >> 11;
        int j = (r & 3) * 512 + bi * 8 + (r >> 2);
        bs[idx] = b_ih[l * 2048 + j] + b_hh[l * 2048 + j];
    }
}

__global__ void k_cvt4(const float4* __restrict__ src, ushort4* __restrict__ dst, long n4) {
    long i = blockIdx.x * (long)blockDim.x + threadIdx.x;
    long stride = (long)gridDim.x * blockDim.x;
    for (; i < n4; i += stride) {
        float4 f = src[i];
        ushort4 u;
        u.x = f2b(f.x); u.y = f2b(f.y); u.z = f2b(f.z); u.w = f2b(f.w);
        dst[i] = u;
    }
}

__global__ void k_embed(const float* __restrict__ emb, const int* __restrict__ dec,
                        float* __restrict__ seqF, unsigned short* __restrict__ seqBp) {
    int t = blockIdx.x;
    for (int i = threadIdx.x; i < BATCH * HDIM; i += blockDim.x) {
        int b = i >> 9, e = i & 511;
        int tok = dec[b * TSTEPS + t];
        float v = emb[(size_t)tok * HDIM + e];
        seqF[((size_t)t * BATCH + b) * HDIM + e] = v;
        seqBp[(size_t)t * 16384 + apack_off(b, e)] = f2b(v);
    }
}

__global__ void k_inith(const float* __restrict__ h0, unsigned short* __restrict__ apack) {
    int idx = blockIdx.x * blockDim.x + threadIdx.x;   // 65536
    int l = idx >> 14, b = (idx >> 9) & 31, d = idx & 511;
    apack[(size_t)(l * 2) * 32768 + apack_off(b, 512 + d)] =
        f2b(h0[((size_t)l * BATCH + b) * HDIM + d]);
}

// ---------------- persistent LSTM: fence-free producer/consumer pipeline ----------------
// 256 blocks (layer l = blk>>6, slice bi = blk&63) x 256 threads.
// Consumers read cross-block data via agent-scope relaxed atomic loads (sc-bypass,
// coherence point) -> NO acquire fence / L2 invalidate. Producers: cached stores +
// one RELEASE fetch_add per step (waitcnt + wbl2 flushes ~2.5KB dirty).
__global__ __launch_bounds__(256, 1) void k_lstm(
    unsigned short* apack,                    // [4][2][32768] bf16 fragment-packed [inp|h]
    const unsigned short* __restrict__ wpack,
    const float* __restrict__ bsum,
    const unsigned short* __restrict__ seqBp, // [64][16384] packed emb (read-only, cached)
    const float* __restrict__ seqF,           // [64][32][512] fp32 emb (read-only, cached)
    float* outF,                              // [4][2][32][512] fp32 residual exchange
    unsigned short* __restrict__ seqOut,      // [64*32][512] final layer out (bf16)
    const float* __restrict__ c0,
    float* __restrict__ outHT, float* __restrict__ outCT,
    unsigned* arrc) {                         // 4 counters, stride 1024 u32 (4KB apart)
    const int l = blockIdx.x >> 6, bi = blockIdx.x & 63;
    const int wave = threadIdx.x >> 6, lane = threadIdx.x & 63;
    const int mi = wave >> 1, ni = wave & 1;
    const int cb = threadIdx.x >> 3, dsl = threadIdx.x & 7;
    const int d = bi * 8 + dsl;

    __shared__ short sW[32768];    // 64 KB W slice
    __shared__ short sA[32768];    // 64 KB A staging
    __shared__ float sG[1024];     //  4 KB gates
    __shared__ short sHexH[512];   //  1 KB h export repack
    __shared__ short sHexO[512];   //  1 KB o export repack

    {   // stationary W slice -> LDS (cached reads, once)
        const unsigned short* wp = wpack + (size_t)blockIdx.x * 32768;
        #pragma unroll
        for (int i = 0; i < 16; ++i) {
            int off = (i * 256 + threadIdx.x) * 8;
            *(bf16x8*)(sW + off) = *(const bf16x8*)(wp + off);
        }
    }
    float4 bias = *(const float4*)(bsum + blockIdx.x * 32 + dsl * 4);
    float c = c0[((size_t)l * BATCH + cb) * HDIM + d];

    unsigned short* A0 = apack + (size_t)(l * 2 + 0) * 32768;
    unsigned short* A1 = apack + (size_t)(l * 2 + 1) * 32768;

    for (int t = 0; t < TSTEPS; ++t) {
        // ---- flow control: 3 conditions polled concurrently by lanes 0/1/2 ----
        if (threadIdx.x == 0 && t > 0)
            while (__hip_atomic_load(&arrc[l * 1024], __ATOMIC_RELAXED,
                                     __HIP_MEMORY_SCOPE_AGENT) < (unsigned)(64 * t))
                __builtin_amdgcn_s_sleep(2);
        if (threadIdx.x == 1 && l > 0)
            while (__hip_atomic_load(&arrc[(l - 1) * 1024], __ATOMIC_RELAXED,
                                     __HIP_MEMORY_SCOPE_AGENT) < (unsigned)(64 * (t + 1)))
                __builtin_amdgcn_s_sleep(2);
        if (threadIdx.x == 2 && l < 3 && t > 0)
            while (__hip_atomic_load(&arrc[(l + 1) * 1024], __ATOMIC_RELAXED,
                                     __HIP_MEMORY_SCOPE_AGENT) < (unsigned)(64 * (t - 1)))
                __builtin_amdgcn_s_sleep(2);
        __syncthreads();

        // ---- residual input: fp32, issued early to hide latency ----
        float inpf;
        if (l == 0) inpf = seqF[((size_t)t * BATCH + cb) * HDIM + d];           // cached
        else inpf = __hip_atomic_load(&outF[(size_t)((l * 2 + (t & 1)) * BATCH + cb) * HDIM + d],
                                      __ATOMIC_RELAXED, __HIP_MEMORY_SCOPE_AGENT);

        // ---- stage A(l, t&1) -> LDS via coherence-point loads (batched) ----
        const unsigned short* Ab = (t & 1) ? A1 : A0;
        const ULL* Abu = (const ULL*)Ab;
        ULL* sAu = (ULL*)sA;
        if (l == 0) {
            const unsigned short* sp = seqBp + (size_t)t * 16384;
            #pragma unroll
            for (int i = 0; i < 8; ++i) {          // inp half: cached (read-only emb)
                int off = (i * 256 + threadIdx.x) * 8;
                *(bf16x8*)(sA + off) = *(const bf16x8*)(sp + off);
            }
            ULL tmp[16];
            #pragma unroll
            for (int i = 0; i < 16; ++i)           // h half: bypass loads, batched
                tmp[i] = __hip_atomic_load(&Abu[(16 + i) * 256 + threadIdx.x],
                                           __ATOMIC_RELAXED, __HIP_MEMORY_SCOPE_AGENT);
            #pragma unroll
            for (int i = 0; i < 16; ++i)
                sAu[(16 + i) * 256 + threadIdx.x] = tmp[i];
        } else {
            ULL tmp[32];
            #pragma unroll
            for (int i = 0; i < 32; ++i)
                tmp[i] = __hip_atomic_load(&Abu[i * 256 + threadIdx.x],
                                           __ATOMIC_RELAXED, __HIP_MEMORY_SCOPE_AGENT);
            #pragma unroll
            for (int i = 0; i < 32; ++i)
                sAu[i * 256 + threadIdx.x] = tmp[i];
        }
        __syncthreads();

        // ---- gates = A @ Wslice^T (each wave one 16x16 tile, K=1024) ----
        f32x4 acc = {0.f, 0.f, 0.f, 0.f};
        const short* abase = sA + mi * 512 + lane * 8;
        const short* wbase = sW + ni * 16384 + lane * 8;
        #pragma unroll
        for (int k0 = 0; k0 < 32; ++k0)
            acc = __builtin_amdgcn_mfma_f32_16x16x32_bf16(
                *(const bf16x8*)(abase + k0 * 1024),
                *(const bf16x8*)(wbase + k0 * 512), acc, 0, 0, 0);

        int gb = mi * 16 + (lane >> 4) * 4;
        int gr = ni * 16 + (lane & 15);
        #pragma unroll
        for (int r = 0; r < 4; ++r) sG[(gb + r) * 32 + gr] = acc[r];
        __syncthreads();

        // ---- cell update (thread owns (cb, d)) ----
        float4 g4 = *(const float4*)(sG + cb * 32 + dsl * 4);
        float gi = g4.x + bias.x, gf = g4.y + bias.y;
        float gg = g4.z + bias.z, go = g4.w + bias.w;
        float ci = sigf(gf) * c + sigf(gi) * tanhf(gg);
        float hi = sigf(go) * tanhf(ci);
        c = ci;
        float o = hi + inpf;

        sHexH[cb * 8 + dsl] = f2b(hi);
        sHexO[cb * 8 + dsl] = f2b(o);
        if (l < 3)    // fp32 residual side-channel (cached store; flushed by release)
            outF[(size_t)(((l + 1) * 2 + (t & 1)) * BATCH + cb) * HDIM + d] = o;
        if (t == TSTEPS - 1) {
            outHT[((size_t)l * BATCH + cb) * HDIM + d] = hi;
            outCT[((size_t)l * BATCH + cb) * HDIM + d] = ci;
        }
        __syncthreads();

        // ---- export: coalesced 16B chunks (disjoint 256B regions per block) ----
        unsigned short* An = ((t + 1) & 1) ? A1 : A0;
        int i = threadIdx.x & 63, cbe = i >> 1, jh = i & 1;
        int lanecode = ((cbe & 15) | ((bi & 3) << 4)) * 2 + jh;
        if (threadIdx.x < 64) {
            int hoff = ((16 + (bi >> 2)) * 2 + (cbe >> 4)) * 128 + lanecode;
            ((ULL*)An)[hoff] = ((const ULL*)sHexH)[i];
        } else if (threadIdx.x < 128) {
            if (l < 3) {
                unsigned short* Anx = apack + (size_t)((l + 1) * 2 + (t & 1)) * 32768;
                int ooff = ((bi >> 2) * 2 + (cbe >> 4)) * 128 + lanecode;
                ((ULL*)Anx)[ooff] = ((const ULL*)sHexO)[i];
            } else {
                ((ULL*)seqOut)[(t * 32 + cbe) * 128 + bi * 2 + jh] = ((const ULL*)sHexO)[i];
            }
        }
        __syncthreads();   // drains all waves' stores (vmcnt0 before s_barrier)

        if (threadIdx.x == 0)   // release: waitcnt + wbl2 (flush dirty) + arrive
            __hip_atomic_fetch_add(&arrc[l * 1024], 1u, __ATOMIC_RELEASE,
                                   __HIP_MEMORY_SCOPE_AGENT);
    }
}

// ---------------- fused classifier + log_softmax over T (verified) ----------------
__global__ __launch_bounds__(256) void k_cls(
    const unsigned short* __restrict__ A,   // seqOut bf16, rows t*B+b, [.,512]
    const unsigned short* __restrict__ W,   // W_cls bf16 [V][512]
    float* __restrict__ out) {              // [B][T][V]
    int b = blockIdx.x & 31;
    int vt = blockIdx.x >> 5;
    int v0 = vt * 128;
    int wave = threadIdx.x >> 6;
    int lane = threadIdx.x & 63;
    int wn0 = v0 + wave * 32;
    int lm = lane & 15;
    int lk = 8 * (lane >> 4);

    f32x4 acc[4][2];
    #pragma unroll
    for (int i = 0; i < 4; ++i)
        #pragma unroll
        for (int j = 0; j < 2; ++j) acc[i][j] = (f32x4)(0.0f);

    for (int k0 = 0; k0 < HDIM; k0 += 32) {
        bf16x8 a[4], bb[2];
        #pragma unroll
        for (int mi = 0; mi < 4; ++mi) {
            int t = mi * 16 + lm;
            a[mi] = *(const bf16x8*)(A + ((size_t)(t * BATCH + b)) * HDIM + k0 + lk);
        }
        #pragma unroll
        for (int ni = 0; ni < 2; ++ni) {
            int v = wn0 + ni * 16 + lm;
            bb[ni] = *(const bf16x8*)(W + (size_t)v * HDIM + k0 + lk);
        }
        #pragma unroll
        for (int mi = 0; mi < 4; ++mi)
            #pragma unroll
            for (int ni = 0; ni < 2; ++ni)
                acc[mi][ni] = __builtin_amdgcn_mfma_f32_16x16x32_bf16(a[mi], bb[ni], acc[mi][ni], 0, 0, 0);
    }

    #pragma unroll
    for (int ni = 0; ni < 2; ++ni) {
        float m = -1e30f;
        #pragma unroll
        for (int mi = 0; mi < 4; ++mi)
            #pragma unroll
            for (int r = 0; r < 4; ++r) m = fmaxf(m, acc[mi][ni][r]);
        m = fmaxf(m, __shfl_xor(m, 16));
        m = fmaxf(m, __shfl_xor(m, 32));
        float s = 0.f;
        #pragma unroll
        for (int mi = 0; mi < 4; ++mi)
            #pragma unroll
            for (int r = 0; r < 4; ++r) s += expf(acc[mi][ni][r] - m);
        s += __shfl_xor(s, 16);
        s += __shfl_xor(s, 32);
        float logZ = m + logf(s);
        int v = wn0 + ni * 16 + lm;
        #pragma unroll
        for (int mi = 0; mi < 4; ++mi) {
            #pragma unroll
            for (int r = 0; r < 4; ++r) {
                int t = mi * 16 + (lane >> 4) * 4 + r;
                out[((size_t)b * TSTEPS + t) * VOCAB + v] = acc[mi][ni][r] - logZ;
            }
        }
    }
}

extern "C" void kernel_launch(void* const* d_in, const int* in_sizes, int n_in,
                              void* d_out, int out_size, void* d_ws, size_t ws_size,
                              hipStream_t stream) {
    const int*   dec   = (const int*)d_in[1];
    const float* h0    = (const float*)d_in[2];
    const float* c0    = (const float*)d_in[3];
    const float* emb   = (const float*)d_in[4];
    const float* W_ih  = (const float*)d_in[5];
    const float* W_hh  = (const float*)d_in[6];
    const float* b_ih  = (const float*)d_in[7];
    const float* b_hh  = (const float*)d_in[8];
    const float* W_cls = (const float*)d_in[9];

    const int LBH = NLAYERS * BATCH * HDIM;           // 65536
    const size_t BTV = (size_t)BATCH * TSTEPS * VOCAB;

    char* ws = (char*)d_ws;
    size_t off = 0;
    auto alloc = [&](size_t bytes) -> void* {
        void* p = ws + off;
        off = (off + bytes + 255) & ~(size_t)255;
        return p;
    };
    unsigned short* wpack  = (unsigned short*)alloc((size_t)NLAYERS * 64 * 2 * 32 * 64 * 8 * 2);
    float*          bsum   = (float*)alloc((size_t)NLAYERS * 64 * 32 * 4);
    unsigned short* wcls16 = (unsigned short*)alloc((size_t)VOCAB * HDIM * 2);
    float*          seqF   = (float*)alloc((size_t)TSTEPS * BATCH * HDIM * 4);
    unsigned short* seqBp  = (unsigned short*)alloc((size_t)TSTEPS * 16384 * 2);
    unsigned short* apack  = (unsigned short*)alloc((size_t)NLAYERS * 2 * 32768 * 2);
    float*          outF   = (float*)alloc((size_t)NLAYERS * 2 * BATCH * HDIM * 4);
    unsigned short* seqOut = (unsigned short*)alloc((size_t)TSTEPS * BATCH * HDIM * 2);
    unsigned*       arrc   = (unsigned*)alloc(16384);

    k_prep_w<<<4096, 256, 0, stream>>>(W_ih, W_hh, wpack);
    k_prep_bias<<<32, 256, 0, stream>>>(b_ih, b_hh, bsum);
    k_cvt4<<<8192, 256, 0, stream>>>((const float4*)W_cls, (ushort4*)wcls16,
                                     (long)VOCAB * HDIM / 4);
    k_embed<<<TSTEPS, 256, 0, stream>>>(emb, dec, seqF, seqBp);
    k_inith<<<256, 256, 0, stream>>>(h0, apack);
    hipMemsetAsync(arrc, 0, 16384, stream);

    k_lstm<<<256, 256, 0, stream>>>(apack, wpack, bsum, seqBp, seqF, outF, seqOut,
                                    c0,
                                    (float*)d_out + BTV,
                                    (float*)d_out + BTV + LBH,
                                    arrc);

    k_cls<<<250 * 32, 256, 0, stream>>>(seqOut, wcls16, (float*)d_out);
}

// Round 6
// 699.559 us; speedup vs baseline: 1.6506x; 1.6506x over previous
//
#include <hip/hip_runtime.h>
#include <math.h>

#define VOCAB 32000
#define HDIM  512
#define NLAYERS 4
#define BATCH 32
#define TSTEPS 64
typedef unsigned long long ULL;

typedef __attribute__((ext_vector_type(8))) short bf16x8;
typedef __attribute__((ext_vector_type(4))) float f32x4;

static __device__ __forceinline__ unsigned short f2b(float f) {
    union { float f; unsigned u; } v; v.f = f;
    return (unsigned short)((v.u + 0x7FFFu + ((v.u >> 16) & 1u)) >> 16);
}
static __device__ __forceinline__ float sigf(float x) { return 1.0f / (1.0f + __expf(-x)); }

// packed offset of element (m,k) in a [32 rows][1024 k] bf16 operand stored in
// MFMA-fragment order: [k0=k/32][mi=m/16][lane][8]
static __device__ __forceinline__ int apack_off(int m, int k) {
    int k0 = k >> 5, mi = m >> 4;
    int lane = (m & 15) | (((k >> 3) & 3) << 4);
    return ((k0 * 2 + mi) * 64 + lane) * 8 + (k & 7);
}

// ---------------- weight prep (verified round 2/3/5) ----------------
__global__ void k_prep_w(const float* __restrict__ W_ih, const float* __restrict__ W_hh,
                         unsigned short* __restrict__ wp) {
    const int total = NLAYERS * 64 * 2 * 32 * 64 * 8;  // 8388608
    for (int idx = blockIdx.x * blockDim.x + threadIdx.x; idx < total;
         idx += gridDim.x * blockDim.x) {
        int sub = idx & 7, lane = (idx >> 3) & 63, k0 = (idx >> 9) & 31;
        int ni = (idx >> 14) & 1, bi = (idx >> 15) & 63, l = idx >> 21;
        int r = ni * 16 + (lane & 15);
        int k = k0 * 32 + ((lane >> 4) << 3) + sub;
        int j = (r & 3) * 512 + bi * 8 + (r >> 2);
        float v = (k < 512) ? W_ih[((size_t)l * 2048 + j) * 512 + k]
                            : W_hh[((size_t)l * 2048 + j) * 512 + (k - 512)];
        wp[idx] = f2b(v);
    }
}

__global__ void k_prep_bias(const float* __restrict__ b_ih, const float* __restrict__ b_hh,
                            float* __restrict__ bs) {
    int idx = blockIdx.x * blockDim.x + threadIdx.x;
    if (idx < NLAYERS * 64 * 32) {
        int r = idx & 31, bi = (idx >> 5) & 63, l = idx >> 11;
        int j = (r & 3) * 512 + bi * 8 + (r >> 2);
        bs[idx] = b_ih[l * 2048 + j] + b_hh[l * 2048 + j];
    }
}

__global__ void k_cvt4(const float4* __restrict__ src, ushort4* __restrict__ dst, long n4) {
    long i = blockIdx.x * (long)blockDim.x + threadIdx.x;
    long stride = (long)gridDim.x * blockDim.x;
    for (; i < n4; i += stride) {
        float4 f = src[i];
        ushort4 u;
        u.x = f2b(f.x); u.y = f2b(f.y); u.z = f2b(f.z); u.w = f2b(f.w);
        dst[i] = u;
    }
}

__global__ void k_embed(const float* __restrict__ emb, const int* __restrict__ dec,
                        float* __restrict__ seqF, unsigned short* __restrict__ seqBp) {
    int t = blockIdx.x;
    for (int i = threadIdx.x; i < BATCH * HDIM; i += blockDim.x) {
        int b = i >> 9, e = i & 511;
        int tok = dec[b * TSTEPS + t];
        float v = emb[(size_t)tok * HDIM + e];
        seqF[((size_t)t * BATCH + b) * HDIM + e] = v;
        seqBp[(size_t)t * 16384 + apack_off(b, e)] = f2b(v);
    }
}

__global__ void k_inith(const float* __restrict__ h0, unsigned short* __restrict__ apack) {
    int idx = blockIdx.x * blockDim.x + threadIdx.x;   // 65536
    int l = idx >> 14, b = (idx >> 9) & 31, d = idx & 511;
    apack[(size_t)(l * 2) * 32768 + apack_off(b, 512 + d)] =
        f2b(h0[((size_t)l * BATCH + b) * HDIM + d]);
}

// ---------------- persistent LSTM: fence-free, RMW-free flag pipeline ----------------
// 256 blocks (layer l = blk>>6, slice bi = blk&63) x 256 threads.
// ALL cross-block traffic via sc1 coherence-point ops: data stores are agent-relaxed
// atomics (no wbl2, no release), each block owns a private flag word (64B apart);
// flag = t+1 stored after s_waitcnt vmcnt(0) + block barrier. Consumers: 3 waves
// spin per-lane on the 64 producer flags of {own, upstream, downstream} layers.
__global__ __launch_bounds__(256, 1) void k_lstm(
    unsigned short* apack,                    // [4][2][32768] bf16 fragment-packed [inp|h]
    const unsigned short* __restrict__ wpack,
    const float* __restrict__ bsum,
    const unsigned short* __restrict__ seqBp, // [64][16384] packed emb (read-only, cached)
    const float* __restrict__ seqF,           // [64][32][512] fp32 emb (read-only, cached)
    float* outF,                              // [4][2][32][512] fp32 residual exchange
    unsigned short* __restrict__ seqOut,      // [64*32][512] final layer out (bf16)
    const float* __restrict__ c0,
    float* __restrict__ outHT, float* __restrict__ outCT,
    unsigned* flags) {                        // [4][64] flags, 64B stride
    const int l = blockIdx.x >> 6, bi = blockIdx.x & 63;
    const int wave = threadIdx.x >> 6, lane = threadIdx.x & 63;
    const int mi = wave >> 1, ni = wave & 1;
    const int cb = threadIdx.x >> 3, dsl = threadIdx.x & 7;
    const int d = bi * 8 + dsl;

    __shared__ short sW[32768];    // 64 KB W slice
    __shared__ short sA[32768];    // 64 KB A staging
    __shared__ float sG[1024];     //  4 KB gates
    __shared__ short sHexH[512];   //  1 KB h export repack
    __shared__ short sHexO[512];   //  1 KB o export repack

    {   // stationary W slice -> LDS (cached reads, once)
        const unsigned short* wp = wpack + (size_t)blockIdx.x * 32768;
        #pragma unroll
        for (int i = 0; i < 16; ++i) {
            int off = (i * 256 + threadIdx.x) * 8;
            *(bf16x8*)(sW + off) = *(const bf16x8*)(wp + off);
        }
    }
    float4 bias = *(const float4*)(bsum + blockIdx.x * 32 + dsl * 4);
    float c = c0[((size_t)l * BATCH + cb) * HDIM + d];

    unsigned short* A0 = apack + (size_t)(l * 2 + 0) * 32768;
    unsigned short* A1 = apack + (size_t)(l * 2 + 1) * 32768;

    for (int t = 0; t < TSTEPS; ++t) {
        // ---- flow control: 3 waves spin per-lane on per-producer flags ----
        if (wave == 0 && t > 0) {                    // own layer finished step t-1
            const unsigned* fp = flags + (l * 64 + lane) * 16;
            while (__hip_atomic_load(fp, __ATOMIC_RELAXED, __HIP_MEMORY_SCOPE_AGENT)
                   < (unsigned)t)
                __builtin_amdgcn_s_sleep(1);
        }
        if (wave == 1 && l > 0) {                    // upstream finished step t
            const unsigned* fp = flags + ((l - 1) * 64 + lane) * 16;
            while (__hip_atomic_load(fp, __ATOMIC_RELAXED, __HIP_MEMORY_SCOPE_AGENT)
                   < (unsigned)(t + 1))
                __builtin_amdgcn_s_sleep(1);
        }
        if (wave == 2 && l < 3 && t > 0) {           // downstream finished step t-1 (back-pressure)
            const unsigned* fp = flags + ((l + 1) * 64 + lane) * 16;
            while (__hip_atomic_load(fp, __ATOMIC_RELAXED, __HIP_MEMORY_SCOPE_AGENT)
                   < (unsigned)(t - 1))
                __builtin_amdgcn_s_sleep(1);
        }
        __syncthreads();

        // ---- residual input: fp32, issued early to hide latency ----
        float inpf;
        if (l == 0) inpf = seqF[((size_t)t * BATCH + cb) * HDIM + d];           // cached
        else inpf = __hip_atomic_load(&outF[(size_t)((l * 2 + (t & 1)) * BATCH + cb) * HDIM + d],
                                      __ATOMIC_RELAXED, __HIP_MEMORY_SCOPE_AGENT);

        // ---- stage A(l, t&1) -> LDS via coherence-point loads (batched) ----
        const unsigned short* Ab = (t & 1) ? A1 : A0;
        const ULL* Abu = (const ULL*)Ab;
        ULL* sAu = (ULL*)sA;
        if (l == 0) {
            const unsigned short* sp = seqBp + (size_t)t * 16384;
            #pragma unroll
            for (int i = 0; i < 8; ++i) {          // inp half: cached (read-only emb)
                int off = (i * 256 + threadIdx.x) * 8;
                *(bf16x8*)(sA + off) = *(const bf16x8*)(sp + off);
            }
            ULL tmp[16];
            #pragma unroll
            for (int i = 0; i < 16; ++i)           // h half: bypass loads, batched
                tmp[i] = __hip_atomic_load(&Abu[(16 + i) * 256 + threadIdx.x],
                                           __ATOMIC_RELAXED, __HIP_MEMORY_SCOPE_AGENT);
            #pragma unroll
            for (int i = 0; i < 16; ++i)
                sAu[(16 + i) * 256 + threadIdx.x] = tmp[i];
        } else {
            ULL tmp[32];
            #pragma unroll
            for (int i = 0; i < 32; ++i)
                tmp[i] = __hip_atomic_load(&Abu[i * 256 + threadIdx.x],
                                           __ATOMIC_RELAXED, __HIP_MEMORY_SCOPE_AGENT);
            #pragma unroll
            for (int i = 0; i < 32; ++i)
                sAu[i * 256 + threadIdx.x] = tmp[i];
        }
        __syncthreads();

        // ---- gates = A @ Wslice^T (each wave one 16x16 tile, K=1024) ----
        f32x4 acc = {0.f, 0.f, 0.f, 0.f};
        const short* abase = sA + mi * 512 + lane * 8;
        const short* wbase = sW + ni * 16384 + lane * 8;
        #pragma unroll
        for (int k0 = 0; k0 < 32; ++k0)
            acc = __builtin_amdgcn_mfma_f32_16x16x32_bf16(
                *(const bf16x8*)(abase + k0 * 1024),
                *(const bf16x8*)(wbase + k0 * 512), acc, 0, 0, 0);

        int gb = mi * 16 + (lane >> 4) * 4;
        int gr = ni * 16 + (lane & 15);
        #pragma unroll
        for (int r = 0; r < 4; ++r) sG[(gb + r) * 32 + gr] = acc[r];
        __syncthreads();

        // ---- cell update (thread owns (cb, d)) ----
        float4 g4 = *(const float4*)(sG + cb * 32 + dsl * 4);
        float gi = g4.x + bias.x, gf = g4.y + bias.y;
        float gg = g4.z + bias.z, go = g4.w + bias.w;
        float ci = sigf(gf) * c + sigf(gi) * tanhf(gg);
        float hi = sigf(go) * tanhf(ci);
        c = ci;
        float o = hi + inpf;

        sHexH[cb * 8 + dsl] = f2b(hi);
        sHexO[cb * 8 + dsl] = f2b(o);
        if (l < 3)    // fp32 residual: sc1 store straight to coherence point
            __hip_atomic_store(&outF[(size_t)(((l + 1) * 2 + (t & 1)) * BATCH + cb) * HDIM + d],
                               o, __ATOMIC_RELAXED, __HIP_MEMORY_SCOPE_AGENT);
        if (t == TSTEPS - 1) {
            outHT[((size_t)l * BATCH + cb) * HDIM + d] = hi;
            outCT[((size_t)l * BATCH + cb) * HDIM + d] = ci;
        }
        __syncthreads();

        // ---- export: coalesced 8B sc1 stores (disjoint 256B regions per block) ----
        unsigned short* An = ((t + 1) & 1) ? A1 : A0;
        int i = threadIdx.x & 63, cbe = i >> 1, jh = i & 1;
        int lanecode = ((cbe & 15) | ((bi & 3) << 4)) * 2 + jh;
        if (threadIdx.x < 64) {
            int hoff = ((16 + (bi >> 2)) * 2 + (cbe >> 4)) * 128 + lanecode;
            __hip_atomic_store(&((ULL*)An)[hoff], ((const ULL*)sHexH)[i],
                               __ATOMIC_RELAXED, __HIP_MEMORY_SCOPE_AGENT);
        } else if (threadIdx.x < 128) {
            if (l < 3) {
                unsigned short* Anx = apack + (size_t)((l + 1) * 2 + (t & 1)) * 32768;
                int ooff = ((bi >> 2) * 2 + (cbe >> 4)) * 128 + lanecode;
                __hip_atomic_store(&((ULL*)Anx)[ooff], ((const ULL*)sHexO)[i],
                                   __ATOMIC_RELAXED, __HIP_MEMORY_SCOPE_AGENT);
            } else {
                ((ULL*)seqOut)[(t * 32 + cbe) * 128 + bi * 2 + jh] = ((const ULL*)sHexO)[i];
            }
        }

        // own stores visible at coherence point, then publish flag = t+1
        asm volatile("s_waitcnt vmcnt(0)" ::: "memory");
        __syncthreads();
        if (threadIdx.x == 0)
            __hip_atomic_store(&flags[(l * 64 + bi) * 16], (unsigned)(t + 1),
                               __ATOMIC_RELAXED, __HIP_MEMORY_SCOPE_AGENT);
    }
}

// ---------------- fused classifier + log_softmax over T (verified) ----------------
__global__ __launch_bounds__(256) void k_cls(
    const unsigned short* __restrict__ A,   // seqOut bf16, rows t*B+b, [.,512]
    const unsigned short* __restrict__ W,   // W_cls bf16 [V][512]
    float* __restrict__ out) {              // [B][T][V]
    int b = blockIdx.x & 31;
    int vt = blockIdx.x >> 5;
    int v0 = vt * 128;
    int wave = threadIdx.x >> 6;
    int lane = threadIdx.x & 63;
    int wn0 = v0 + wave * 32;
    int lm = lane & 15;
    int lk = 8 * (lane >> 4);

    f32x4 acc[4][2];
    #pragma unroll
    for (int i = 0; i < 4; ++i)
        #pragma unroll
        for (int j = 0; j < 2; ++j) acc[i][j] = (f32x4)(0.0f);

    for (int k0 = 0; k0 < HDIM; k0 += 32) {
        bf16x8 a[4], bb[2];
        #pragma unroll
        for (int mi = 0; mi < 4; ++mi) {
            int t = mi * 16 + lm;
            a[mi] = *(const bf16x8*)(A + ((size_t)(t * BATCH + b)) * HDIM + k0 + lk);
        }
        #pragma unroll
        for (int ni = 0; ni < 2; ++ni) {
            int v = wn0 + ni * 16 + lm;
            bb[ni] = *(const bf16x8*)(W + (size_t)v * HDIM + k0 + lk);
        }
        #pragma unroll
        for (int mi = 0; mi < 4; ++mi)
            #pragma unroll
            for (int ni = 0; ni < 2; ++ni)
                acc[mi][ni] = __builtin_amdgcn_mfma_f32_16x16x32_bf16(a[mi], bb[ni], acc[mi][ni], 0, 0, 0);
    }

    #pragma unroll
    for (int ni = 0; ni < 2; ++ni) {
        float m = -1e30f;
        #pragma unroll
        for (int mi = 0; mi < 4; ++mi)
            #pragma unroll
            for (int r = 0; r < 4; ++r) m = fmaxf(m, acc[mi][ni][r]);
        m = fmaxf(m, __shfl_xor(m, 16));
        m = fmaxf(m, __shfl_xor(m, 32));
        float s = 0.f;
        #pragma unroll
        for (int mi = 0; mi < 4; ++mi)
            #pragma unroll
            for (int r = 0; r < 4; ++r) s += expf(acc[mi][ni][r] - m);
        s += __shfl_xor(s, 16);
        s += __shfl_xor(s, 32);
        float logZ = m + logf(s);
        int v = wn0 + ni * 16 + lm;
        #pragma unroll
        for (int mi = 0; mi < 4; ++mi) {
            #pragma unroll
            for (int r = 0; r < 4; ++r) {
                int t = mi * 16 + (lane >> 4) * 4 + r;
                out[((size_t)b * TSTEPS + t) * VOCAB + v] = acc[mi][ni][r] - logZ;
            }
        }
    }
}

extern "C" void kernel_launch(void* const* d_in, const int* in_sizes, int n_in,
                              void* d_out, int out_size, void* d_ws, size_t ws_size,
                              hipStream_t stream) {
    const int*   dec   = (const int*)d_in[1];
    const float* h0    = (const float*)d_in[2];
    const float* c0    = (const float*)d_in[3];
    const float* emb   = (const float*)d_in[4];
    const float* W_ih  = (const float*)d_in[5];
    const float* W_hh  = (const float*)d_in[6];
    const float* b_ih  = (const float*)d_in[7];
    const float* b_hh  = (const float*)d_in[8];
    const float* W_cls = (const float*)d_in[9];

    const int LBH = NLAYERS * BATCH * HDIM;           // 65536
    const size_t BTV = (size_t)BATCH * TSTEPS * VOCAB;

    char* ws = (char*)d_ws;
    size_t off = 0;
    auto alloc = [&](size_t bytes) -> void* {
        void* p = ws + off;
        off = (off + bytes + 255) & ~(size_t)255;
        return p;
    };
    unsigned short* wpack  = (unsigned short*)alloc((size_t)NLAYERS * 64 * 2 * 32 * 64 * 8 * 2);
    float*          bsum   = (float*)alloc((size_t)NLAYERS * 64 * 32 * 4);
    unsigned short* wcls16 = (unsigned short*)alloc((size_t)VOCAB * HDIM * 2);
    float*          seqF   = (float*)alloc((size_t)TSTEPS * BATCH * HDIM * 4);
    unsigned short* seqBp  = (unsigned short*)alloc((size_t)TSTEPS * 16384 * 2);
    unsigned short* apack  = (unsigned short*)alloc((size_t)NLAYERS * 2 * 32768 * 2);
    float*          outF   = (float*)alloc((size_t)NLAYERS * 2 * BATCH * HDIM * 4);
    unsigned short* seqOut = (unsigned short*)alloc((size_t)TSTEPS * BATCH * HDIM * 2);
    unsigned*       flags  = (unsigned*)alloc(16384);

    k_prep_w<<<4096, 256, 0, stream>>>(W_ih, W_hh, wpack);
    k_prep_bias<<<32, 256, 0, stream>>>(b_ih, b_hh, bsum);
    k_cvt4<<<8192, 256, 0, stream>>>((const float4*)W_cls, (ushort4*)wcls16,
                                     (long)VOCAB * HDIM / 4);
    k_embed<<<TSTEPS, 256, 0, stream>>>(emb, dec, seqF, seqBp);
    k_inith<<<256, 256, 0, stream>>>(h0, apack);
    hipMemsetAsync(flags, 0, 16384, stream);

    k_lstm<<<256, 256, 0, stream>>>(apack, wpack, bsum, seqBp, seqF, outF, seqOut,
                                    c0,
                                    (float*)d_out + BTV,
                                    (float*)d_out + BTV + LBH,
                                    flags);

    k_cls<<<250 * 32, 256, 0, stream>>>(seqOut, wcls16, (float*)d_out);
}

// Round 7
// 499.315 us; speedup vs baseline: 2.3126x; 1.4010x over previous
//
#include <hip/hip_runtime.h>
#include <math.h>

#define VOCAB 32000
#define HDIM  512
#define NLAYERS 4
#define BATCH 32
#define TSTEPS 64
typedef unsigned long long ULL;

typedef __attribute__((ext_vector_type(8))) short bf16x8;
typedef __attribute__((ext_vector_type(4))) float f32x4;

static __device__ __forceinline__ unsigned short f2b(float f) {
    union { float f; unsigned u; } v; v.f = f;
    return (unsigned short)((v.u + 0x7FFFu + ((v.u >> 16) & 1u)) >> 16);
}
static __device__ __forceinline__ float sigf(float x) { return 1.0f / (1.0f + __expf(-x)); }

// packed offset of element (m,k) in a [32 rows][1024 k] bf16 operand stored in
// MFMA-fragment order: [k0=k/32][mi=m/16][lane][8]
static __device__ __forceinline__ int apack_off(int m, int k) {
    int k0 = k >> 5, mi = m >> 4;
    int lane = (m & 15) | (((k >> 3) & 3) << 4);
    return ((k0 * 2 + mi) * 64 + lane) * 8 + (k & 7);
}

// ---------------- weight prep (verified round 2/3/5/6) ----------------
__global__ void k_prep_w(const float* __restrict__ W_ih, const float* __restrict__ W_hh,
                         unsigned short* __restrict__ wp) {
    const int total = NLAYERS * 64 * 2 * 32 * 64 * 8;  // 8388608
    for (int idx = blockIdx.x * blockDim.x + threadIdx.x; idx < total;
         idx += gridDim.x * blockDim.x) {
        int sub = idx & 7, lane = (idx >> 3) & 63, k0 = (idx >> 9) & 31;
        int ni = (idx >> 14) & 1, bi = (idx >> 15) & 63, l = idx >> 21;
        int r = ni * 16 + (lane & 15);
        int k = k0 * 32 + ((lane >> 4) << 3) + sub;
        int j = (r & 3) * 512 + bi * 8 + (r >> 2);
        float v = (k < 512) ? W_ih[((size_t)l * 2048 + j) * 512 + k]
                            : W_hh[((size_t)l * 2048 + j) * 512 + (k - 512)];
        wp[idx] = f2b(v);
    }
}

__global__ void k_prep_bias(const float* __restrict__ b_ih, const float* __restrict__ b_hh,
                            float* __restrict__ bs) {
    int idx = blockIdx.x * blockDim.x + threadIdx.x;
    if (idx < NLAYERS * 64 * 32) {
        int r = idx & 31, bi = (idx >> 5) & 63, l = idx >> 11;
        int j = (r & 3) * 512 + bi * 8 + (r >> 2);
        bs[idx] = b_ih[l * 2048 + j] + b_hh[l * 2048 + j];
    }
}

// ---------------- W_cls -> bf16, MFMA-fragment packed ----------------
// chunk = (((vt*4 + w)*2 + ni)*16 + k0)*64 + lane ; element (v,k):
//   v = vt*128 + w*32 + ni*16 + (lane&15), k = k0*32 + ((lane>>4)<<3) + sub
__global__ void k_prep_wcls(const float* __restrict__ W_cls, unsigned short* __restrict__ wp) {
    int idx8 = blockIdx.x * blockDim.x + threadIdx.x;   // 2048000 chunks
    int lane = idx8 & 63, k0 = (idx8 >> 6) & 15, ni = (idx8 >> 10) & 1;
    int w = (idx8 >> 11) & 3, vt = idx8 >> 13;
    int v = vt * 128 + w * 32 + ni * 16 + (lane & 15);
    int kb = k0 * 32 + ((lane >> 4) << 3);
    const float* src = W_cls + (size_t)v * 512 + kb;
    float4 f0 = *(const float4*)(src);
    float4 f1 = *(const float4*)(src + 4);
    bf16x8 u;
    u[0] = (short)f2b(f0.x); u[1] = (short)f2b(f0.y);
    u[2] = (short)f2b(f0.z); u[3] = (short)f2b(f0.w);
    u[4] = (short)f2b(f1.x); u[5] = (short)f2b(f1.y);
    u[6] = (short)f2b(f1.z); u[7] = (short)f2b(f1.w);
    *(bf16x8*)(wp + (size_t)idx8 * 8) = u;
}

__global__ void k_embed(const float* __restrict__ emb, const int* __restrict__ dec,
                        float* __restrict__ seqF, unsigned short* __restrict__ seqBp) {
    int t = blockIdx.x;
    for (int i = threadIdx.x; i < BATCH * HDIM; i += blockDim.x) {
        int b = i >> 9, e = i & 511;
        int tok = dec[b * TSTEPS + t];
        float v = emb[(size_t)tok * HDIM + e];
        seqF[((size_t)t * BATCH + b) * HDIM + e] = v;
        seqBp[(size_t)t * 16384 + apack_off(b, e)] = f2b(v);
    }
}

__global__ void k_inith(const float* __restrict__ h0, unsigned short* __restrict__ apack) {
    int idx = blockIdx.x * blockDim.x + threadIdx.x;   // 65536
    int l = idx >> 14, b = (idx >> 9) & 31, d = idx & 511;
    apack[(size_t)(l * 2) * 32768 + apack_off(b, 512 + d)] =
        f2b(h0[((size_t)l * BATCH + b) * HDIM + d]);
}

// ---------------- persistent LSTM (verified round 6, fence-free flag pipeline) ----------
// Only change: final-layer output now exported in per-b MFMA-fragment-packed layout
// (A-operand of the classifier): chunk = ((b*16 + k0)*4 + mi)*64 + lane.
__global__ __launch_bounds__(256, 1) void k_lstm(
    unsigned short* apack,                    // [4][2][32768] bf16 fragment-packed [inp|h]
    const unsigned short* __restrict__ wpack,
    const float* __restrict__ bsum,
    const unsigned short* __restrict__ seqBp, // [64][16384] packed emb (read-only, cached)
    const float* __restrict__ seqF,           // [64][32][512] fp32 emb (read-only, cached)
    float* outF,                              // [4][2][32][512] fp32 residual exchange
    unsigned short* __restrict__ seqOut,      // [32][16][4][64][8] final layer out, packed
    const float* __restrict__ c0,
    float* __restrict__ outHT, float* __restrict__ outCT,
    unsigned* flags) {                        // [4][64] flags, 64B stride
    const int l = blockIdx.x >> 6, bi = blockIdx.x & 63;
    const int wave = threadIdx.x >> 6, lane = threadIdx.x & 63;
    const int mi = wave >> 1, ni = wave & 1;
    const int cb = threadIdx.x >> 3, dsl = threadIdx.x & 7;
    const int d = bi * 8 + dsl;

    __shared__ short sW[32768];    // 64 KB W slice
    __shared__ short sA[32768];    // 64 KB A staging
    __shared__ float sG[1024];     //  4 KB gates
    __shared__ short sHexH[512];   //  1 KB h export repack
    __shared__ short sHexO[512];   //  1 KB o export repack

    {   // stationary W slice -> LDS (cached reads, once)
        const unsigned short* wp = wpack + (size_t)blockIdx.x * 32768;
        #pragma unroll
        for (int i = 0; i < 16; ++i) {
            int off = (i * 256 + threadIdx.x) * 8;
            *(bf16x8*)(sW + off) = *(const bf16x8*)(wp + off);
        }
    }
    float4 bias = *(const float4*)(bsum + blockIdx.x * 32 + dsl * 4);
    float c = c0[((size_t)l * BATCH + cb) * HDIM + d];

    unsigned short* A0 = apack + (size_t)(l * 2 + 0) * 32768;
    unsigned short* A1 = apack + (size_t)(l * 2 + 1) * 32768;

    for (int t = 0; t < TSTEPS; ++t) {
        // ---- flow control: 3 waves spin per-lane on per-producer flags ----
        if (wave == 0 && t > 0) {
            const unsigned* fp = flags + (l * 64 + lane) * 16;
            while (__hip_atomic_load(fp, __ATOMIC_RELAXED, __HIP_MEMORY_SCOPE_AGENT)
                   < (unsigned)t)
                __builtin_amdgcn_s_sleep(1);
        }
        if (wave == 1 && l > 0) {
            const unsigned* fp = flags + ((l - 1) * 64 + lane) * 16;
            while (__hip_atomic_load(fp, __ATOMIC_RELAXED, __HIP_MEMORY_SCOPE_AGENT)
                   < (unsigned)(t + 1))
                __builtin_amdgcn_s_sleep(1);
        }
        if (wave == 2 && l < 3 && t > 0) {
            const unsigned* fp = flags + ((l + 1) * 64 + lane) * 16;
            while (__hip_atomic_load(fp, __ATOMIC_RELAXED, __HIP_MEMORY_SCOPE_AGENT)
                   < (unsigned)(t - 1))
                __builtin_amdgcn_s_sleep(1);
        }
        __syncthreads();

        // ---- residual input: fp32, issued early to hide latency ----
        float inpf;
        if (l == 0) inpf = seqF[((size_t)t * BATCH + cb) * HDIM + d];
        else inpf = __hip_atomic_load(&outF[(size_t)((l * 2 + (t & 1)) * BATCH + cb) * HDIM + d],
                                      __ATOMIC_RELAXED, __HIP_MEMORY_SCOPE_AGENT);

        // ---- stage A(l, t&1) -> LDS via coherence-point loads (batched) ----
        const unsigned short* Ab = (t & 1) ? A1 : A0;
        const ULL* Abu = (const ULL*)Ab;
        ULL* sAu = (ULL*)sA;
        if (l == 0) {
            const unsigned short* sp = seqBp + (size_t)t * 16384;
            #pragma unroll
            for (int i = 0; i < 8; ++i) {
                int off = (i * 256 + threadIdx.x) * 8;
                *(bf16x8*)(sA + off) = *(const bf16x8*)(sp + off);
            }
            ULL tmp[16];
            #pragma unroll
            for (int i = 0; i < 16; ++i)
                tmp[i] = __hip_atomic_load(&Abu[(16 + i) * 256 + threadIdx.x],
                                           __ATOMIC_RELAXED, __HIP_MEMORY_SCOPE_AGENT);
            #pragma unroll
            for (int i = 0; i < 16; ++i)
                sAu[(16 + i) * 256 + threadIdx.x] = tmp[i];
        } else {
            ULL tmp[32];
            #pragma unroll
            for (int i = 0; i < 32; ++i)
                tmp[i] = __hip_atomic_load(&Abu[i * 256 + threadIdx.x],
                                           __ATOMIC_RELAXED, __HIP_MEMORY_SCOPE_AGENT);
            #pragma unroll
            for (int i = 0; i < 32; ++i)
                sAu[i * 256 + threadIdx.x] = tmp[i];
        }
        __syncthreads();

        // ---- gates = A @ Wslice^T (each wave one 16x16 tile, K=1024) ----
        f32x4 acc = {0.f, 0.f, 0.f, 0.f};
        const short* abase = sA + mi * 512 + lane * 8;
        const short* wbase = sW + ni * 16384 + lane * 8;
        #pragma unroll
        for (int k0 = 0; k0 < 32; ++k0)
            acc = __builtin_amdgcn_mfma_f32_16x16x32_bf16(
                *(const bf16x8*)(abase + k0 * 1024),
                *(const bf16x8*)(wbase + k0 * 512), acc, 0, 0, 0);

        int gb = mi * 16 + (lane >> 4) * 4;
        int gr = ni * 16 + (lane & 15);
        #pragma unroll
        for (int r = 0; r < 4; ++r) sG[(gb + r) * 32 + gr] = acc[r];
        __syncthreads();

        // ---- cell update (thread owns (cb, d)) ----
        float4 g4 = *(const float4*)(sG + cb * 32 + dsl * 4);
        float gi = g4.x + bias.x, gf = g4.y + bias.y;
        float gg = g4.z + bias.z, go = g4.w + bias.w;
        float ci = sigf(gf) * c + sigf(gi) * tanhf(gg);
        float hi = sigf(go) * tanhf(ci);
        c = ci;
        float o = hi + inpf;

        sHexH[cb * 8 + dsl] = f2b(hi);
        sHexO[cb * 8 + dsl] = f2b(o);
        if (l < 3)
            __hip_atomic_store(&outF[(size_t)(((l + 1) * 2 + (t & 1)) * BATCH + cb) * HDIM + d],
                               o, __ATOMIC_RELAXED, __HIP_MEMORY_SCOPE_AGENT);
        if (t == TSTEPS - 1) {
            outHT[((size_t)l * BATCH + cb) * HDIM + d] = hi;
            outCT[((size_t)l * BATCH + cb) * HDIM + d] = ci;
        }
        __syncthreads();

        // ---- export: coalesced 8B sc1 stores (disjoint regions per block) ----
        unsigned short* An = ((t + 1) & 1) ? A1 : A0;
        int i = threadIdx.x & 63, cbe = i >> 1, jh = i & 1;
        int lanecode = ((cbe & 15) | ((bi & 3) << 4)) * 2 + jh;
        if (threadIdx.x < 64) {
            int hoff = ((16 + (bi >> 2)) * 2 + (cbe >> 4)) * 128 + lanecode;
            __hip_atomic_store(&((ULL*)An)[hoff], ((const ULL*)sHexH)[i],
                               __ATOMIC_RELAXED, __HIP_MEMORY_SCOPE_AGENT);
        } else if (threadIdx.x < 128) {
            if (l < 3) {
                unsigned short* Anx = apack + (size_t)((l + 1) * 2 + (t & 1)) * 32768;
                int ooff = ((bi >> 2) * 2 + (cbe >> 4)) * 128 + lanecode;
                __hip_atomic_store(&((ULL*)Anx)[ooff], ((const ULL*)sHexO)[i],
                                   __ATOMIC_RELAXED, __HIP_MEMORY_SCOPE_AGENT);
            } else {
                // fragment-packed classifier A-operand: element (t, d=bi*8+dsl) of batch cbe
                // chunk = ((cbe*16 + (bi>>2))*4 + (t>>4))*64 + ((t&15)|((bi&3)<<4))
                int ulidx = ((((cbe * 16 + (bi >> 2)) * 4 + (t >> 4)) * 64 +
                             ((t & 15) | ((bi & 3) << 4))) * 2) + jh;
                ((ULL*)seqOut)[ulidx] = ((const ULL*)sHexO)[i];
            }
        }

        asm volatile("s_waitcnt vmcnt(0)" ::: "memory");
        __syncthreads();
        if (threadIdx.x == 0)
            __hip_atomic_store(&flags[(l * 64 + bi) * 16], (unsigned)(t + 1),
                               __ATOMIC_RELAXED, __HIP_MEMORY_SCOPE_AGENT);
    }
}

// ---------------- fused classifier + log_softmax over T, packed operands ----------------
// block = (b = blk&31, vt = blk>>5); 4 waves x (64t x 32v). All K-loop loads are
// lane-contiguous dwordx4. Epilogue transposes through LDS for 512B-coalesced stores.
__global__ __launch_bounds__(256) void k_cls(
    const unsigned short* __restrict__ Ap,   // [32][16][4][64][8] packed seq
    const unsigned short* __restrict__ Wp,   // [250][4][2][16][64][8] packed W_cls
    float* __restrict__ out) {               // [B][T][V]
    int b = blockIdx.x & 31;
    int vt = blockIdx.x >> 5;
    int wave = threadIdx.x >> 6;
    int lane = threadIdx.x & 63;

    __shared__ float sL[64 * 132];   // padded stride 132 (33 KB)

    const unsigned short* abase = Ap + (size_t)b * 32768 + lane * 8;
    const unsigned short* wbase = Wp + (size_t)(vt * 4 + wave) * 16384 + lane * 8;

    f32x4 acc[4][2];
    #pragma unroll
    for (int i = 0; i < 4; ++i)
        #pragma unroll
        for (int j = 0; j < 2; ++j) acc[i][j] = (f32x4)(0.0f);

    #pragma unroll 4
    for (int k0 = 0; k0 < 16; ++k0) {
        bf16x8 a[4], bb[2];
        #pragma unroll
        for (int mi = 0; mi < 4; ++mi)
            a[mi] = *(const bf16x8*)(abase + (k0 * 4 + mi) * 512);
        #pragma unroll
        for (int ni = 0; ni < 2; ++ni)
            bb[ni] = *(const bf16x8*)(wbase + ni * 8192 + k0 * 512);
        #pragma unroll
        for (int mi = 0; mi < 4; ++mi)
            #pragma unroll
            for (int ni = 0; ni < 2; ++ni)
                acc[mi][ni] = __builtin_amdgcn_mfma_f32_16x16x32_bf16(a[mi], bb[ni], acc[mi][ni], 0, 0, 0);
    }

    // per column v: logsumexp over 64 t (regs r, frags mi, lane groups via xor 16/32)
    #pragma unroll
    for (int ni = 0; ni < 2; ++ni) {
        float m = -1e30f;
        #pragma unroll
        for (int mi = 0; mi < 4; ++mi)
            #pragma unroll
            for (int r = 0; r < 4; ++r) m = fmaxf(m, acc[mi][ni][r]);
        m = fmaxf(m, __shfl_xor(m, 16));
        m = fmaxf(m, __shfl_xor(m, 32));
        float s = 0.f;
        #pragma unroll
        for (int mi = 0; mi < 4; ++mi)
            #pragma unroll
            for (int r = 0; r < 4; ++r) s += expf(acc[mi][ni][r] - m);
        s += __shfl_xor(s, 16);
        s += __shfl_xor(s, 32);
        float logZ = m + logf(s);
        int col = wave * 32 + ni * 16 + (lane & 15);
        #pragma unroll
        for (int mi = 0; mi < 4; ++mi) {
            #pragma unroll
            for (int r = 0; r < 4; ++r) {
                int row = mi * 16 + (lane >> 4) * 4 + r;
                sL[row * 132 + col] = acc[mi][ni][r] - logZ;
            }
        }
    }
    __syncthreads();

    // coalesced stores: 512B contiguous per t-row chunk
    float* obase = out + (size_t)b * TSTEPS * VOCAB + vt * 128;
    #pragma unroll
    for (int it = 0; it < 8; ++it) {
        int idx = it * 256 + threadIdx.x;
        int row = idx >> 5, c4 = (idx & 31) * 4;
        float4 val = *(const float4*)(sL + row * 132 + c4);
        *(float4*)(obase + (size_t)row * VOCAB + c4) = val;
    }
}

extern "C" void kernel_launch(void* const* d_in, const int* in_sizes, int n_in,
                              void* d_out, int out_size, void* d_ws, size_t ws_size,
                              hipStream_t stream) {
    const int*   dec   = (const int*)d_in[1];
    const float* h0    = (const float*)d_in[2];
    const float* c0    = (const float*)d_in[3];
    const float* emb   = (const float*)d_in[4];
    const float* W_ih  = (const float*)d_in[5];
    const float* W_hh  = (const float*)d_in[6];
    const float* b_ih  = (const float*)d_in[7];
    const float* b_hh  = (const float*)d_in[8];
    const float* W_cls = (const float*)d_in[9];

    const int LBH = NLAYERS * BATCH * HDIM;           // 65536
    const size_t BTV = (size_t)BATCH * TSTEPS * VOCAB;

    char* ws = (char*)d_ws;
    size_t off = 0;
    auto alloc = [&](size_t bytes) -> void* {
        void* p = ws + off;
        off = (off + bytes + 255) & ~(size_t)255;
        return p;
    };
    unsigned short* wpack  = (unsigned short*)alloc((size_t)NLAYERS * 64 * 2 * 32 * 64 * 8 * 2);
    float*          bsum   = (float*)alloc((size_t)NLAYERS * 64 * 32 * 4);
    unsigned short* wpackC = (unsigned short*)alloc((size_t)VOCAB * HDIM * 2);
    float*          seqF   = (float*)alloc((size_t)TSTEPS * BATCH * HDIM * 4);
    unsigned short* seqBp  = (unsigned short*)alloc((size_t)TSTEPS * 16384 * 2);
    unsigned short* apack  = (unsigned short*)alloc((size_t)NLAYERS * 2 * 32768 * 2);
    float*          outF   = (float*)alloc((size_t)NLAYERS * 2 * BATCH * HDIM * 4);
    unsigned short* apackC = (unsigned short*)alloc((size_t)TSTEPS * BATCH * HDIM * 2);
    unsigned*       flags  = (unsigned*)alloc(16384);

    k_prep_w<<<4096, 256, 0, stream>>>(W_ih, W_hh, wpack);
    k_prep_bias<<<32, 256, 0, stream>>>(b_ih, b_hh, bsum);
    k_prep_wcls<<<8000, 256, 0, stream>>>(W_cls, wpackC);
    k_embed<<<TSTEPS, 256, 0, stream>>>(emb, dec, seqF, seqBp);
    k_inith<<<256, 256, 0, stream>>>(h0, apack);
    hipMemsetAsync(flags, 0, 16384, stream);

    k_lstm<<<256, 256, 0, stream>>>(apack, wpack, bsum, seqBp, seqF, outF, apackC,
                                    c0,
                                    (float*)d_out + BTV,
                                    (float*)d_out + BTV + LBH,
                                    flags);

    k_cls<<<250 * 32, 256, 0, stream>>>(apackC, wpackC, (float*)d_out);
}